// Round 1
// 2178.786 us; speedup vs baseline: 1.0183x; 1.0183x over previous
//
#include <hip/hip_runtime.h>

typedef __bf16 bf16x8 __attribute__((ext_vector_type(8)));
typedef float f32x4 __attribute__((ext_vector_type(4)));

// ---------- helpers ----------
__device__ __forceinline__ unsigned short f2bf(float f) {
  unsigned u = __float_as_uint(f);
  u += 0x7FFFu + ((u >> 16) & 1u);
  return (unsigned short)(u >> 16);
}

__device__ __forceinline__ void async16(const void* g, void* l) {
  // global -> LDS direct copy, 16B/lane; LDS dest = wave-uniform base + lane*16
  __builtin_amdgcn_global_load_lds((const __attribute__((address_space(1))) void*)g,
                                   (__attribute__((address_space(3))) void*)l,
                                   16, 0, 0);
}

// ---------- conversion kernels ----------
__global__ void cvt_f32_bf16_k(const float4* __restrict__ in, ushort4* __restrict__ out) {
  int i = blockIdx.x * blockDim.x + threadIdx.x;
  float4 v = in[i];
  ushort4 o;
  o.x = f2bf(v.x); o.y = f2bf(v.y); o.z = f2bf(v.z); o.w = f2bf(v.w);
  out[i] = o;
}

__global__ void cvt_i32_bf16_k(const int4* __restrict__ in, ushort4* __restrict__ out) {
  int i = blockIdx.x * blockDim.x + threadIdx.x;
  int4 v = in[i];
  ushort4 o;
  o.x = f2bf((float)v.x); o.y = f2bf((float)v.y);
  o.z = f2bf((float)v.z); o.w = f2bf((float)v.w);  // |v|<=128: exact in bf16
  out[i] = o;
}

// ---------- shared schedule machinery ----------
// Raw barrier (no implicit vmcnt/lgkm drain) with compiler memory fences.
#define BAR() do { asm volatile("" ::: "memory"); __builtin_amdgcn_s_barrier(); \
                   asm volatile("" ::: "memory"); } while (0)

// one 128x64 bf16 chunk = 2 global_load_lds per thread (8 waves x 16 rows)
#define STAGE2(GP, LP) do { async16((GP), (LP)); \
    async16((GP) + 8 * (size_t)K, (LP) + 8 * 64); } while (0)

#define LOAD_A(AF, CURA, HA)                                                   \
  _Pragma("unroll") for (int mi = 0; mi < 4; ++mi)                             \
  _Pragma("unroll") for (int kk = 0; kk < 2; ++kk)                             \
    AF[mi][kk] = *(const bf16x8*)&(CURA)[((HA) * 128 + wrow + mi * 16 + r) * 64 \
                                         + (((kk * 4 + q) ^ rx) * 8)];

#define LOAD_B(BF, CURB, HB)                                                   \
  _Pragma("unroll") for (int ni = 0; ni < 2; ++ni)                             \
  _Pragma("unroll") for (int kk = 0; kk < 2; ++kk)                             \
    BF[ni][kk] = *(const bf16x8*)&(CURB)[((HB) * 128 + wcol + ni * 16 + r) * 64 \
                                         + (((kk * 4 + q) ^ rx) * 8)];

#define MFMA16(ACC, AF, BF)                                                    \
  __builtin_amdgcn_s_setprio(1);                                               \
  _Pragma("unroll") for (int kk = 0; kk < 2; ++kk)                             \
  _Pragma("unroll") for (int ni = 0; ni < 2; ++ni)                             \
  _Pragma("unroll") for (int mi = 0; mi < 4; ++mi)                             \
    ACC[mi][ni] = __builtin_amdgcn_mfma_f32_16x16x32_bf16(                     \
        AF[mi][kk], BF[ni][kk], ACC[mi][ni], 0, 0, 0);                         \
  __builtin_amdgcn_s_setprio(0);

// ---------- fused gate+up GEMM with SwiGLU epilogue ----------
// Tile 256(M) x 128(N), BK=64, 8 waves (2M x 4N per 128-row half).
// Double-buffered LDS (128 KiB), phase-split schedule with counted vmcnt:
//   phase 0: (gate, A-half0)  stage A0(t+1)   gate vmcnt(4)
//   phase 1: (up,   A-half0)  stage Bg(t+1)   gate vmcnt(4)
//   phase 2: (gate, A-half1)  stage Bu(t+1)   (no gate)
//   phase 3: (up,   A-half1)  stage A1(t+1)   gate vmcnt(4)   <- tile boundary
// Chunk first-use next iter: A0,Bg @p0; Bu @p1; A1 @p2 -> every gate leaves
// exactly the last 2 chunks (4 loads) in flight; never vmcnt(0) mid-loop.
__global__ __launch_bounds__(512, 2)
void gemm_gateup(const unsigned short* __restrict__ A,
                 const unsigned short* __restrict__ Bg,
                 const unsigned short* __restrict__ Bu,
                 const float* __restrict__ gsc, const float* __restrict__ usc,
                 unsigned short* __restrict__ Hout,
                 int M, int N, int K) {
  __shared__ unsigned short sA [2 * 256 * 64];   // 64 KiB
  __shared__ unsigned short sBg[2 * 128 * 64];   // 32 KiB
  __shared__ unsigned short sBu[2 * 128 * 64];   // 32 KiB

  const int tid  = threadIdx.x;
  const int lane = tid & 63;
  const int wv   = tid >> 6;            // 0..7

  // grouped ordering: 112 n-tiles, 16 m-tiles; group = 16N x 16M = 256 blocks
  const int bid = blockIdx.x;
  const int grp = bid >> 8;             // 0..6
  const int rem = bid & 255;
  const int bN  = ((grp << 4) + (rem & 15)) * 128;
  const int bM  = (rem >> 4) * 256;

  // staging: each wave loads 16 rows of every 128-row chunk (2 issues)
  const int srow = lane >> 3;                    // 0..7
  const int gcol = ((lane & 7) ^ srow) * 8;      // pre-swizzled 16B chunk col

  const unsigned short* gA0 = A  + (size_t)(bM +       wv * 16 + srow) * K + gcol;
  const unsigned short* gA1 = A  + (size_t)(bM + 128 + wv * 16 + srow) * K + gcol;
  const unsigned short* gBg = Bg + (size_t)(bN +       wv * 16 + srow) * K + gcol;
  const unsigned short* gBu = Bu + (size_t)(bN +       wv * 16 + srow) * K + gcol;

  const int r    = lane & 15;           // m/n within 16-frag
  const int q    = lane >> 4;           // k-group
  const int rx   = r & 7;               // read-side swizzle term
  const int wrow = (wv >> 2) * 64;      // row band within a 128-row half
  const int wcol = (wv & 3) * 32;       // col band within the 128-col tile

  f32x4 accg0[4][2], accg1[4][2], accu0[4][2], accu1[4][2];
#pragma unroll
  for (int i = 0; i < 4; i++)
#pragma unroll
    for (int j = 0; j < 2; j++) {
      accg0[i][j] = f32x4{0.f, 0.f, 0.f, 0.f};
      accg1[i][j] = f32x4{0.f, 0.f, 0.f, 0.f};
      accu0[i][j] = f32x4{0.f, 0.f, 0.f, 0.f};
      accu1[i][j] = f32x4{0.f, 0.f, 0.f, 0.f};
    }

  const int NT = K >> 6;

  // prologue: stage tile 0 in consumption order; leave Bu,A1 in flight
  STAGE2(gA0, &sA [ wv * 16 * 64]);
  STAGE2(gBg, &sBg[ wv * 16 * 64]);
  STAGE2(gBu, &sBu[ wv * 16 * 64]);
  STAGE2(gA1, &sA [(128 + wv * 16) * 64]);
  asm volatile("s_waitcnt vmcnt(4)" ::: "memory");
  __builtin_amdgcn_s_barrier();

  int cur = 0;
  for (int t = 0; t < NT; ++t) {
    const unsigned short* curA  = sA  + cur * (256 * 64);
    const unsigned short* curBg = sBg + cur * (128 * 64);
    const unsigned short* curBu = sBu + cur * (128 * 64);
    unsigned short* nxtA  = sA  + (cur ^ 1) * (256 * 64);
    unsigned short* nxtBg = sBg + (cur ^ 1) * (128 * 64);
    unsigned short* nxtBu = sBu + (cur ^ 1) * (128 * 64);
    const int  kn = (t + 1) << 6;
    const bool st = (t + 1) < NT;

    bf16x8 af0[4][2], af1[4][2];

    // ---- phase 0: gate x A-half0 ----
    {
      bf16x8 bfr[2][2];
      LOAD_A(af0, curA, 0);
      LOAD_B(bfr, curBg, 0);
      if (st) STAGE2(gA0 + kn, nxtA + wv * 16 * 64);
      BAR();
      MFMA16(accg0, af0, bfr);
      if (st) asm volatile("s_waitcnt vmcnt(4)" ::: "memory");  // Bu(t) landed
      else    asm volatile("s_waitcnt vmcnt(2)" ::: "memory");
      BAR();
    }
    // ---- phase 1: up x A-half0 (A-frags reused) ----
    {
      bf16x8 bfr[2][2];
      LOAD_B(bfr, curBu, 0);
      if (st) STAGE2(gBg + kn, nxtBg + wv * 16 * 64);
      BAR();
      MFMA16(accu0, af0, bfr);
      if (st) asm volatile("s_waitcnt vmcnt(4)" ::: "memory");  // A1(t) landed
      else    asm volatile("s_waitcnt vmcnt(0)" ::: "memory");
      BAR();
    }
    // ---- phase 2: gate x A-half1 ----
    {
      bf16x8 bfr[2][2];
      LOAD_A(af1, curA, 1);
      LOAD_B(bfr, curBg, 0);
      if (st) STAGE2(gBu + kn, nxtBu + wv * 16 * 64);
      BAR();
      MFMA16(accg1, af1, bfr);
      BAR();
    }
    // ---- phase 3: up x A-half1 ----
    {
      bf16x8 bfr[2][2];
      LOAD_B(bfr, curBu, 0);
      if (st) STAGE2(gA1 + kn, nxtA + (128 + wv * 16) * 64);
      BAR();
      MFMA16(accu1, af1, bfr);
      if (st) {
        asm volatile("s_waitcnt vmcnt(4)" ::: "memory");  // A0,Bg(t+1) landed
        BAR();
      }
    }
    cur ^= 1;
  }

  // epilogue: scale, SwiGLU, store bf16. D layout: col=lane&15, row=q*4+rr
#pragma unroll
  for (int ni = 0; ni < 2; ++ni) {
    const int col = bN + wcol + ni * 16 + r;
    const float gs = gsc[col], us = usc[col];
#pragma unroll
    for (int mi = 0; mi < 4; ++mi) {
#pragma unroll
      for (int rr = 0; rr < 4; ++rr) {
        const int row0 = bM + wrow + mi * 16 + q * 4 + rr;
        float g0 = accg0[mi][ni][rr] * gs;
        float u0 = accu0[mi][ni][rr] * us;
        Hout[(size_t)row0 * N + col] = f2bf((g0 / (1.f + __expf(-g0))) * u0);
        const int row1 = row0 + 128;
        float g1 = accg1[mi][ni][rr] * gs;
        float u1 = accu1[mi][ni][rr] * us;
        Hout[(size_t)row1 * N + col] = f2bf((g1 / (1.f + __expf(-g1))) * u1);
      }
    }
  }
}

// ---------- down GEMM, 256x256 tile, same phase/vmcnt schedule ----------
//   phase 0: (A0,B0) stage A0(t+1)  gate vmcnt(4)
//   phase 1: (A0,B1) stage B0(t+1)  gate vmcnt(4)
//   phase 2: (A1,B0) stage B1(t+1)
//   phase 3: (A1,B1) stage A1(t+1)  gate vmcnt(4)
__global__ __launch_bounds__(512, 2)
void gemm_down(const unsigned short* __restrict__ A,
               const unsigned short* __restrict__ B,
               const float* __restrict__ dsc,
               float* __restrict__ out,
               int M, int N, int K) {
  __shared__ unsigned short sA[2 * 256 * 64];   // 64 KiB
  __shared__ unsigned short sB[2 * 256 * 64];   // 64 KiB

  const int tid  = threadIdx.x;
  const int lane = tid & 63;
  const int wv   = tid >> 6;

  // grid = 16 x 16 = 256 blocks (exactly one per CU)
  const int bM = (blockIdx.x >> 4) * 256;
  const int bN = (blockIdx.x & 15) * 256;

  const int srow = lane >> 3;
  const int gcol = ((lane & 7) ^ srow) * 8;

  const unsigned short* gA0 = A + (size_t)(bM +       wv * 16 + srow) * K + gcol;
  const unsigned short* gA1 = A + (size_t)(bM + 128 + wv * 16 + srow) * K + gcol;
  const unsigned short* gB0 = B + (size_t)(bN +       wv * 16 + srow) * K + gcol;
  const unsigned short* gB1 = B + (size_t)(bN + 128 + wv * 16 + srow) * K + gcol;

  const int r    = lane & 15;
  const int q    = lane >> 4;
  const int rx   = r & 7;
  const int wrow = (wv >> 2) * 64;
  const int wcol = (wv & 3) * 32;

  f32x4 a00[4][2], a01[4][2], a10[4][2], a11[4][2];
#pragma unroll
  for (int i = 0; i < 4; i++)
#pragma unroll
    for (int j = 0; j < 2; j++) {
      a00[i][j] = f32x4{0.f, 0.f, 0.f, 0.f};
      a01[i][j] = f32x4{0.f, 0.f, 0.f, 0.f};
      a10[i][j] = f32x4{0.f, 0.f, 0.f, 0.f};
      a11[i][j] = f32x4{0.f, 0.f, 0.f, 0.f};
    }

  const int NT = K >> 6;

  STAGE2(gA0, &sA[ wv * 16 * 64]);
  STAGE2(gB0, &sB[ wv * 16 * 64]);
  STAGE2(gB1, &sB[(128 + wv * 16) * 64]);
  STAGE2(gA1, &sA[(128 + wv * 16) * 64]);
  asm volatile("s_waitcnt vmcnt(4)" ::: "memory");
  __builtin_amdgcn_s_barrier();

  int cur = 0;
  for (int t = 0; t < NT; ++t) {
    const unsigned short* curA = sA + cur * (256 * 64);
    const unsigned short* curB = sB + cur * (256 * 64);
    unsigned short* nxtA = sA + (cur ^ 1) * (256 * 64);
    unsigned short* nxtB = sB + (cur ^ 1) * (256 * 64);
    const int  kn = (t + 1) << 6;
    const bool st = (t + 1) < NT;

    bf16x8 af0[4][2], af1[4][2];

    // ---- phase 0: (A0, B0) ----
    {
      bf16x8 bfr[2][2];
      LOAD_A(af0, curA, 0);
      LOAD_B(bfr, curB, 0);
      if (st) STAGE2(gA0 + kn, nxtA + wv * 16 * 64);
      BAR();
      MFMA16(a00, af0, bfr);
      if (st) asm volatile("s_waitcnt vmcnt(4)" ::: "memory");  // B1(t) landed
      else    asm volatile("s_waitcnt vmcnt(2)" ::: "memory");
      BAR();
    }
    // ---- phase 1: (A0, B1) ----
    {
      bf16x8 bfr[2][2];
      LOAD_B(bfr, curB, 1);
      if (st) STAGE2(gB0 + kn, nxtB + wv * 16 * 64);
      BAR();
      MFMA16(a01, af0, bfr);
      if (st) asm volatile("s_waitcnt vmcnt(4)" ::: "memory");  // A1(t) landed
      else    asm volatile("s_waitcnt vmcnt(0)" ::: "memory");
      BAR();
    }
    // ---- phase 2: (A1, B0) ----
    {
      bf16x8 bfr[2][2];
      LOAD_A(af1, curA, 1);
      LOAD_B(bfr, curB, 0);
      if (st) STAGE2(gB1 + kn, nxtB + (128 + wv * 16) * 64);
      BAR();
      MFMA16(a10, af1, bfr);
      BAR();
    }
    // ---- phase 3: (A1, B1) ----
    {
      bf16x8 bfr[2][2];
      LOAD_B(bfr, curB, 1);
      if (st) STAGE2(gA1 + kn, nxtA + (128 + wv * 16) * 64);
      BAR();
      MFMA16(a11, af1, bfr);
      if (st) {
        asm volatile("s_waitcnt vmcnt(4)" ::: "memory");  // A0,B0(t+1) landed
        BAR();
      }
    }
    cur ^= 1;
  }

#pragma unroll
  for (int ni = 0; ni < 2; ++ni) {
    const int c0 = bN + wcol + ni * 16 + r;
    const int c1 = c0 + 128;
    const float s0 = dsc[c0], s1 = dsc[c1];
#pragma unroll
    for (int mi = 0; mi < 4; ++mi) {
#pragma unroll
      for (int rr = 0; rr < 4; ++rr) {
        const int row0 = bM + wrow + mi * 16 + q * 4 + rr;
        const int row1 = row0 + 128;
        out[(size_t)row0 * N + c0] = a00[mi][ni][rr] * s0;
        out[(size_t)row0 * N + c1] = a01[mi][ni][rr] * s1;
        out[(size_t)row1 * N + c0] = a10[mi][ni][rr] * s0;
        out[(size_t)row1 * N + c1] = a11[mi][ni][rr] * s1;
      }
    }
  }
}

// ---------- launch ----------
extern "C" void kernel_launch(void* const* d_in, const int* in_sizes, int n_in,
                              void* d_out, int out_size, void* d_ws, size_t ws_size,
                              hipStream_t stream) {
  constexpr int M  = 4096;   // B*S
  constexpr int Hd = 4096;   // hidden
  constexpr int Id = 14336;  // intermediate

  const float* x   = (const float*)d_in[0];
  const int*   gwq = (const int*)  d_in[1];
  const float* gsc = (const float*)d_in[2];
  const int*   uwq = (const int*)  d_in[3];
  const float* usc = (const float*)d_in[4];
  const int*   dwq = (const int*)  d_in[5];
  const float* dsc = (const float*)d_in[6];
  float* out = (float*)d_out;

  // ws layout (bf16/ushort elems): xb | w0 (gate, later down) | wu | h
  unsigned short* xb = (unsigned short*)d_ws;
  unsigned short* w0 = xb + (size_t)M * Hd;
  unsigned short* wu = w0 + (size_t)Id * Hd;
  unsigned short* hb = wu + (size_t)Id * Hd;

  cvt_f32_bf16_k<<<(M * Hd) / 1024, 256, 0, stream>>>((const float4*)x, (ushort4*)xb);
  cvt_i32_bf16_k<<<((size_t)Id * Hd) / 1024, 256, 0, stream>>>((const int4*)gwq, (ushort4*)w0);
  cvt_i32_bf16_k<<<((size_t)Id * Hd) / 1024, 256, 0, stream>>>((const int4*)uwq, (ushort4*)wu);

  // fused gate+up + SwiGLU -> h (bf16); 16 M-tiles x 112 N-tiles, grouped
  gemm_gateup<<<(M / 256) * (Id / 128), 512, 0, stream>>>(xb, w0, wu, gsc, usc, hb, M, Id, Hd);

  // reuse w0 region for down weights
  cvt_i32_bf16_k<<<((size_t)Hd * Id) / 1024, 256, 0, stream>>>((const int4*)dwq, (ushort4*)w0);

  // down GEMM -> fp32 out; 16 x 16 = 256 blocks, one per CU
  gemm_down<<<(M / 256) * (Hd / 256), 512, 0, stream>>>(hb, w0, dsc, out, M, Hd, Id);
}

// Round 2
// 2063.226 us; speedup vs baseline: 1.0753x; 1.0560x over previous
//
#include <hip/hip_runtime.h>

typedef __bf16 bf16x8 __attribute__((ext_vector_type(8)));
typedef float f32x4 __attribute__((ext_vector_type(4)));

// ---------- helpers ----------
__device__ __forceinline__ unsigned short f2bf(float f) {
  unsigned u = __float_as_uint(f);
  u += 0x7FFFu + ((u >> 16) & 1u);
  return (unsigned short)(u >> 16);
}

__device__ __forceinline__ void async16(const void* g, void* l) {
  // global -> LDS direct copy, 16B/lane; LDS dest = wave-uniform base + lane*16
  __builtin_amdgcn_global_load_lds((const __attribute__((address_space(1))) void*)g,
                                   (__attribute__((address_space(3))) void*)l,
                                   16, 0, 0);
}

// ---------- conversion kernels ----------
__global__ void cvt_f32_bf16_k(const float4* __restrict__ in, ushort4* __restrict__ out) {
  int i = blockIdx.x * blockDim.x + threadIdx.x;
  float4 v = in[i];
  ushort4 o;
  o.x = f2bf(v.x); o.y = f2bf(v.y); o.z = f2bf(v.z); o.w = f2bf(v.w);
  out[i] = o;
}

__global__ void cvt_i32_bf16_k(const int4* __restrict__ in, ushort4* __restrict__ out) {
  int i = blockIdx.x * blockDim.x + threadIdx.x;
  int4 v = in[i];
  ushort4 o;
  o.x = f2bf((float)v.x); o.y = f2bf((float)v.y);
  o.z = f2bf((float)v.z); o.w = f2bf((float)v.w);  // |v|<=128: exact in bf16
  out[i] = o;
}

// ---------- fused gate+up GEMM with SwiGLU epilogue (R0-proven version) ----------
// Block tile 128(M) x 128(N), BK=64; wave tile 64x64 dual (gate+up) 4x4 frags.
// XOR-swizzled LDS (16B chunk ^ row&7): ds_read_b128 2-way = conflict-free.
// 49 KB LDS -> 2 blocks/CU: inter-block overlap hides the barrier drains.
// Grouped launch order: 8 N-tiles x all M-tiles per group -> B weights stream
// HBM once, A + B-chunk stay L2/LLC resident.
__global__ __launch_bounds__(256, 2)
void gemm_gateup(const unsigned short* __restrict__ A,
                 const unsigned short* __restrict__ Bg,
                 const unsigned short* __restrict__ Bu,
                 const float* __restrict__ gsc, const float* __restrict__ usc,
                 unsigned short* __restrict__ Hout,
                 int M, int N, int K) {
  __shared__ unsigned short sA[128 * 64];
  __shared__ unsigned short sBg[128 * 64];
  __shared__ unsigned short sBu[128 * 64];

  const int tid  = threadIdx.x;
  const int lane = tid & 63;
  const int wv   = tid >> 6;           // 0..3

  // grouped ordering: NN=112 n-tiles, MM=32 m-tiles, GN=8 -> 256 blocks/group
  const int bid = blockIdx.x;
  const int grp = bid >> 8;            // /256
  const int rem = bid & 255;
  const int bN  = ((grp << 3) + (rem & 7)) * 128;
  const int bM  = (rem >> 3) * 128;

  // staging: async16 covers 8 rows x 128B; lane row=lane>>3, phys chunk=lane&7;
  // logical chunk = phys ^ (row&7) -> constant per-lane global offset:
  const int srow = lane >> 3;                    // 0..7
  const int gcol = ((lane & 7) ^ srow) * 8;      // element offset of 16B chunk

  const unsigned short* gA  = A  + (size_t)(bM + wv * 32 + srow) * K + gcol;
  const unsigned short* gBg = Bg + (size_t)(bN + wv * 32 + srow) * K + gcol;
  const unsigned short* gBu = Bu + (size_t)(bN + wv * 32 + srow) * K + gcol;
  unsigned short* lA  = &sA [(wv * 32) * 64];
  unsigned short* lBg = &sBg[(wv * 32) * 64];
  unsigned short* lBu = &sBu[(wv * 32) * 64];

  const int r  = lane & 15;            // m (A) / n (B) within 16-tile
  const int q  = lane >> 4;            // k-group
  const int rx = r & 7;                // read-side swizzle term
  const int wm = (wv >> 1) * 64;
  const int wn = (wv & 1) * 64;

  f32x4 accg[4][4], accu[4][4];
#pragma unroll
  for (int i = 0; i < 4; i++)
#pragma unroll
    for (int j = 0; j < 4; j++) {
      accg[i][j] = f32x4{0.f, 0.f, 0.f, 0.f};
      accu[i][j] = f32x4{0.f, 0.f, 0.f, 0.f};
    }

  for (int k0 = 0; k0 < K; k0 += 64) {
    const unsigned short* pA = gA + k0;
    async16(pA,                  lA);
    async16(pA +  8 * (size_t)K, lA +  8 * 64);
    async16(pA + 16 * (size_t)K, lA + 16 * 64);
    async16(pA + 24 * (size_t)K, lA + 24 * 64);
    const unsigned short* pG = gBg + k0;
    async16(pG,                  lBg);
    async16(pG +  8 * (size_t)K, lBg +  8 * 64);
    async16(pG + 16 * (size_t)K, lBg + 16 * 64);
    async16(pG + 24 * (size_t)K, lBg + 24 * 64);
    const unsigned short* pU = gBu + k0;
    async16(pU,                  lBu);
    async16(pU +  8 * (size_t)K, lBu +  8 * 64);
    async16(pU + 16 * (size_t)K, lBu + 16 * 64);
    async16(pU + 24 * (size_t)K, lBu + 24 * 64);
    __syncthreads();

#pragma unroll
    for (int kk = 0; kk < 2; ++kk) {
      const int pc = ((kk * 4 + q) ^ rx) * 8;   // physical chunk offset (elems)
      bf16x8 af[4];
#pragma unroll
      for (int mi = 0; mi < 4; mi++)
        af[mi] = *(const bf16x8*)&sA[(wm + mi * 16 + r) * 64 + pc];
#pragma unroll
      for (int ni = 0; ni < 4; ni++) {
        bf16x8 bg = *(const bf16x8*)&sBg[(wn + ni * 16 + r) * 64 + pc];
        bf16x8 bu = *(const bf16x8*)&sBu[(wn + ni * 16 + r) * 64 + pc];
#pragma unroll
        for (int mi = 0; mi < 4; mi++) {
          accg[mi][ni] = __builtin_amdgcn_mfma_f32_16x16x32_bf16(af[mi], bg, accg[mi][ni], 0, 0, 0);
          accu[mi][ni] = __builtin_amdgcn_mfma_f32_16x16x32_bf16(af[mi], bu, accu[mi][ni], 0, 0, 0);
        }
      }
    }
    __syncthreads();
  }

  // epilogue: scale, SwiGLU, store bf16. D layout: col=lane&15, row=q*4+rr
#pragma unroll
  for (int ni = 0; ni < 4; ni++) {
    const int col = bN + wn + ni * 16 + r;
    const float gs = gsc[col], us = usc[col];
#pragma unroll
    for (int mi = 0; mi < 4; mi++) {
#pragma unroll
      for (int rr = 0; rr < 4; rr++) {
        const int row = bM + wm + mi * 16 + q * 4 + rr;
        float g = accg[mi][ni][rr] * gs;
        float u = accu[mi][ni][rr] * us;
        float hv = (g / (1.f + __expf(-g))) * u;   // silu(g)*u
        Hout[(size_t)row * N + col] = f2bf(hv);
      }
    }
  }
}

// ---------- shared schedule machinery (down GEMM) ----------
// Raw barrier (no implicit vmcnt/lgkm drain) with compiler memory fences.
#define BAR() do { asm volatile("" ::: "memory"); __builtin_amdgcn_s_barrier(); \
                   asm volatile("" ::: "memory"); } while (0)

// one 128x64 bf16 chunk = 2 global_load_lds per thread (8 waves x 16 rows)
#define STAGE2(GP, LP) do { async16((GP), (LP)); \
    async16((GP) + 8 * (size_t)K, (LP) + 8 * 64); } while (0)

#define LOAD_A(AF, CURA, HA)                                                   \
  _Pragma("unroll") for (int mi = 0; mi < 4; ++mi)                             \
  _Pragma("unroll") for (int kk = 0; kk < 2; ++kk)                             \
    AF[mi][kk] = *(const bf16x8*)&(CURA)[((HA) * 128 + wrow + mi * 16 + r) * 64 \
                                         + (((kk * 4 + q) ^ rx) * 8)];

#define LOAD_B(BF, CURB, HB)                                                   \
  _Pragma("unroll") for (int ni = 0; ni < 2; ++ni)                             \
  _Pragma("unroll") for (int kk = 0; kk < 2; ++kk)                             \
    BF[ni][kk] = *(const bf16x8*)&(CURB)[((HB) * 128 + wcol + ni * 16 + r) * 64 \
                                         + (((kk * 4 + q) ^ rx) * 8)];

#define MFMA16(ACC, AF, BF)                                                    \
  __builtin_amdgcn_s_setprio(1);                                               \
  _Pragma("unroll") for (int kk = 0; kk < 2; ++kk)                             \
  _Pragma("unroll") for (int ni = 0; ni < 2; ++ni)                             \
  _Pragma("unroll") for (int mi = 0; mi < 4; ++mi)                             \
    ACC[mi][ni] = __builtin_amdgcn_mfma_f32_16x16x32_bf16(                     \
        AF[mi][kk], BF[ni][kk], ACC[mi][ni], 0, 0, 0);                         \
  __builtin_amdgcn_s_setprio(0);

// ---------- down GEMM, 256x256 tile, phase/vmcnt schedule (R1-proven) ----------
//   phase 0: (A0,B0) stage A0(t+1)  gate vmcnt(4)
//   phase 1: (A0,B1) stage B0(t+1)  gate vmcnt(4)
//   phase 2: (A1,B0) stage B1(t+1)
//   phase 3: (A1,B1) stage A1(t+1)  gate vmcnt(4)
// NEW: XCD-chunked bijective block swizzle (nwg=256 = 8 XCDs x 32): each XCD's
// 32 blocks = 2 M-rows x 16 N-tiles -> shared A K-slabs hit its private L2.
__global__ __launch_bounds__(512, 2)
void gemm_down(const unsigned short* __restrict__ A,
               const unsigned short* __restrict__ B,
               const float* __restrict__ dsc,
               float* __restrict__ out,
               int M, int N, int K) {
  __shared__ unsigned short sA[2 * 256 * 64];   // 64 KiB
  __shared__ unsigned short sB[2 * 256 * 64];   // 64 KiB

  const int tid  = threadIdx.x;
  const int lane = tid & 63;
  const int wv   = tid >> 6;

  // grid = 16 x 16 = 256 blocks (one per CU); XCD-chunked swizzle (bijective)
  const int bid  = blockIdx.x;
  const int wgid = (bid & 7) * 32 + (bid >> 3);
  const int bM = (wgid >> 4) * 256;
  const int bN = (wgid & 15) * 256;

  const int srow = lane >> 3;
  const int gcol = ((lane & 7) ^ srow) * 8;

  const unsigned short* gA0 = A + (size_t)(bM +       wv * 16 + srow) * K + gcol;
  const unsigned short* gA1 = A + (size_t)(bM + 128 + wv * 16 + srow) * K + gcol;
  const unsigned short* gB0 = B + (size_t)(bN +       wv * 16 + srow) * K + gcol;
  const unsigned short* gB1 = B + (size_t)(bN + 128 + wv * 16 + srow) * K + gcol;

  const int r    = lane & 15;
  const int q    = lane >> 4;
  const int rx   = r & 7;
  const int wrow = (wv >> 2) * 64;
  const int wcol = (wv & 3) * 32;

  f32x4 a00[4][2], a01[4][2], a10[4][2], a11[4][2];
#pragma unroll
  for (int i = 0; i < 4; i++)
#pragma unroll
    for (int j = 0; j < 2; j++) {
      a00[i][j] = f32x4{0.f, 0.f, 0.f, 0.f};
      a01[i][j] = f32x4{0.f, 0.f, 0.f, 0.f};
      a10[i][j] = f32x4{0.f, 0.f, 0.f, 0.f};
      a11[i][j] = f32x4{0.f, 0.f, 0.f, 0.f};
    }

  const int NT = K >> 6;

  STAGE2(gA0, &sA[ wv * 16 * 64]);
  STAGE2(gB0, &sB[ wv * 16 * 64]);
  STAGE2(gB1, &sB[(128 + wv * 16) * 64]);
  STAGE2(gA1, &sA[(128 + wv * 16) * 64]);
  asm volatile("s_waitcnt vmcnt(4)" ::: "memory");
  __builtin_amdgcn_s_barrier();

  int cur = 0;
  for (int t = 0; t < NT; ++t) {
    const unsigned short* curA = sA + cur * (256 * 64);
    const unsigned short* curB = sB + cur * (256 * 64);
    unsigned short* nxtA = sA + (cur ^ 1) * (256 * 64);
    unsigned short* nxtB = sB + (cur ^ 1) * (256 * 64);
    const int  kn = (t + 1) << 6;
    const bool st = (t + 1) < NT;

    bf16x8 af0[4][2], af1[4][2];

    // ---- phase 0: (A0, B0) ----
    {
      bf16x8 bfr[2][2];
      LOAD_A(af0, curA, 0);
      LOAD_B(bfr, curB, 0);
      if (st) STAGE2(gA0 + kn, nxtA + wv * 16 * 64);
      BAR();
      MFMA16(a00, af0, bfr);
      if (st) asm volatile("s_waitcnt vmcnt(4)" ::: "memory");  // B1(t) landed
      else    asm volatile("s_waitcnt vmcnt(2)" ::: "memory");
      BAR();
    }
    // ---- phase 1: (A0, B1) ----
    {
      bf16x8 bfr[2][2];
      LOAD_B(bfr, curB, 1);
      if (st) STAGE2(gB0 + kn, nxtB + wv * 16 * 64);
      BAR();
      MFMA16(a01, af0, bfr);
      if (st) asm volatile("s_waitcnt vmcnt(4)" ::: "memory");  // A1(t) landed
      else    asm volatile("s_waitcnt vmcnt(0)" ::: "memory");
      BAR();
    }
    // ---- phase 2: (A1, B0) ----
    {
      bf16x8 bfr[2][2];
      LOAD_A(af1, curA, 1);
      LOAD_B(bfr, curB, 0);
      if (st) STAGE2(gB1 + kn, nxtB + (128 + wv * 16) * 64);
      BAR();
      MFMA16(a10, af1, bfr);
      BAR();
    }
    // ---- phase 3: (A1, B1) ----
    {
      bf16x8 bfr[2][2];
      LOAD_B(bfr, curB, 1);
      if (st) STAGE2(gA1 + kn, nxtA + (128 + wv * 16) * 64);
      BAR();
      MFMA16(a11, af1, bfr);
      if (st) {
        asm volatile("s_waitcnt vmcnt(4)" ::: "memory");  // A0,B0(t+1) landed
        BAR();
      }
    }
    cur ^= 1;
  }

#pragma unroll
  for (int ni = 0; ni < 2; ++ni) {
    const int c0 = bN + wcol + ni * 16 + r;
    const int c1 = c0 + 128;
    const float s0 = dsc[c0], s1 = dsc[c1];
#pragma unroll
    for (int mi = 0; mi < 4; ++mi) {
#pragma unroll
      for (int rr = 0; rr < 4; ++rr) {
        const int row0 = bM + wrow + mi * 16 + q * 4 + rr;
        const int row1 = row0 + 128;
        out[(size_t)row0 * N + c0] = a00[mi][ni][rr] * s0;
        out[(size_t)row0 * N + c1] = a01[mi][ni][rr] * s1;
        out[(size_t)row1 * N + c0] = a10[mi][ni][rr] * s0;
        out[(size_t)row1 * N + c1] = a11[mi][ni][rr] * s1;
      }
    }
  }
}

// ---------- launch ----------
extern "C" void kernel_launch(void* const* d_in, const int* in_sizes, int n_in,
                              void* d_out, int out_size, void* d_ws, size_t ws_size,
                              hipStream_t stream) {
  constexpr int M  = 4096;   // B*S
  constexpr int Hd = 4096;   // hidden
  constexpr int Id = 14336;  // intermediate

  const float* x   = (const float*)d_in[0];
  const int*   gwq = (const int*)  d_in[1];
  const float* gsc = (const float*)d_in[2];
  const int*   uwq = (const int*)  d_in[3];
  const float* usc = (const float*)d_in[4];
  const int*   dwq = (const int*)  d_in[5];
  const float* dsc = (const float*)d_in[6];
  float* out = (float*)d_out;

  // ws layout (bf16/ushort elems): xb | w0 (gate, later down) | wu | h
  unsigned short* xb = (unsigned short*)d_ws;
  unsigned short* w0 = xb + (size_t)M * Hd;
  unsigned short* wu = w0 + (size_t)Id * Hd;
  unsigned short* hb = wu + (size_t)Id * Hd;

  cvt_f32_bf16_k<<<(M * Hd) / 1024, 256, 0, stream>>>((const float4*)x, (ushort4*)xb);
  cvt_i32_bf16_k<<<((size_t)Id * Hd) / 1024, 256, 0, stream>>>((const int4*)gwq, (ushort4*)w0);
  cvt_i32_bf16_k<<<((size_t)Id * Hd) / 1024, 256, 0, stream>>>((const int4*)uwq, (ushort4*)wu);

  // fused gate+up + SwiGLU -> h (bf16); grid = 112*32 blocks, grouped internally
  gemm_gateup<<<(Id / 128) * (M / 128), 256, 0, stream>>>(xb, w0, wu, gsc, usc, hb, M, Id, Hd);

  // reuse w0 region for down weights
  cvt_i32_bf16_k<<<((size_t)Hd * Id) / 1024, 256, 0, stream>>>((const int4*)dwq, (ushort4*)w0);

  // down GEMM -> fp32 out; 16 x 16 = 256 blocks, one per CU, XCD-swizzled
  gemm_down<<<(M / 256) * (Hd / 256), 512, 0, stream>>>(hb, w0, dsc, out, M, Hd, Id);
}

// Round 3
// 2054.973 us; speedup vs baseline: 1.0796x; 1.0040x over previous
//
#include <hip/hip_runtime.h>

typedef __bf16 bf16x8 __attribute__((ext_vector_type(8)));
typedef float f32x4 __attribute__((ext_vector_type(4)));

// ---------- helpers ----------
__device__ __forceinline__ unsigned short f2bf(float f) {
  unsigned u = __float_as_uint(f);
  u += 0x7FFFu + ((u >> 16) & 1u);
  return (unsigned short)(u >> 16);
}

__device__ __forceinline__ void async16(const void* g, void* l) {
  // global -> LDS direct copy, 16B/lane; LDS dest = wave-uniform base + lane*16
  __builtin_amdgcn_global_load_lds((const __attribute__((address_space(1))) void*)g,
                                   (__attribute__((address_space(3))) void*)l,
                                   16, 0, 0);
}

// ---------- conversion kernels ----------
__global__ void cvt_f32_bf16_k(const float4* __restrict__ in, ushort4* __restrict__ out) {
  int i = blockIdx.x * blockDim.x + threadIdx.x;
  float4 v = in[i];
  ushort4 o;
  o.x = f2bf(v.x); o.y = f2bf(v.y); o.z = f2bf(v.z); o.w = f2bf(v.w);
  out[i] = o;
}

__global__ void cvt_i32_bf16_k(const int4* __restrict__ in, ushort4* __restrict__ out) {
  int i = blockIdx.x * blockDim.x + threadIdx.x;
  int4 v = in[i];
  ushort4 o;
  o.x = f2bf((float)v.x); o.y = f2bf((float)v.y);
  o.z = f2bf((float)v.z); o.w = f2bf((float)v.w);  // |v|<=128: exact in bf16
  out[i] = o;
}

// ---------- fused gate+up GEMM with SwiGLU epilogue (R0-proven, unchanged) ----------
// Block tile 128(M) x 128(N), BK=64; wave tile 64x64 dual (gate+up) 4x4 frags.
// XOR-swizzled LDS; 49 KB LDS -> 2 blocks/CU inter-block overlap; grouped launch.
__global__ __launch_bounds__(256, 2)
void gemm_gateup(const unsigned short* __restrict__ A,
                 const unsigned short* __restrict__ Bg,
                 const unsigned short* __restrict__ Bu,
                 const float* __restrict__ gsc, const float* __restrict__ usc,
                 unsigned short* __restrict__ Hout,
                 int M, int N, int K) {
  __shared__ unsigned short sA[128 * 64];
  __shared__ unsigned short sBg[128 * 64];
  __shared__ unsigned short sBu[128 * 64];

  const int tid  = threadIdx.x;
  const int lane = tid & 63;
  const int wv   = tid >> 6;           // 0..3

  const int bid = blockIdx.x;
  const int grp = bid >> 8;            // /256
  const int rem = bid & 255;
  const int bN  = ((grp << 3) + (rem & 7)) * 128;
  const int bM  = (rem >> 3) * 128;

  const int srow = lane >> 3;                    // 0..7
  const int gcol = ((lane & 7) ^ srow) * 8;      // element offset of 16B chunk

  const unsigned short* gA  = A  + (size_t)(bM + wv * 32 + srow) * K + gcol;
  const unsigned short* gBg = Bg + (size_t)(bN + wv * 32 + srow) * K + gcol;
  const unsigned short* gBu = Bu + (size_t)(bN + wv * 32 + srow) * K + gcol;
  unsigned short* lA  = &sA [(wv * 32) * 64];
  unsigned short* lBg = &sBg[(wv * 32) * 64];
  unsigned short* lBu = &sBu[(wv * 32) * 64];

  const int r  = lane & 15;
  const int q  = lane >> 4;
  const int rx = r & 7;
  const int wm = (wv >> 1) * 64;
  const int wn = (wv & 1) * 64;

  f32x4 accg[4][4], accu[4][4];
#pragma unroll
  for (int i = 0; i < 4; i++)
#pragma unroll
    for (int j = 0; j < 4; j++) {
      accg[i][j] = f32x4{0.f, 0.f, 0.f, 0.f};
      accu[i][j] = f32x4{0.f, 0.f, 0.f, 0.f};
    }

  for (int k0 = 0; k0 < K; k0 += 64) {
    const unsigned short* pA = gA + k0;
    async16(pA,                  lA);
    async16(pA +  8 * (size_t)K, lA +  8 * 64);
    async16(pA + 16 * (size_t)K, lA + 16 * 64);
    async16(pA + 24 * (size_t)K, lA + 24 * 64);
    const unsigned short* pG = gBg + k0;
    async16(pG,                  lBg);
    async16(pG +  8 * (size_t)K, lBg +  8 * 64);
    async16(pG + 16 * (size_t)K, lBg + 16 * 64);
    async16(pG + 24 * (size_t)K, lBg + 24 * 64);
    const unsigned short* pU = gBu + k0;
    async16(pU,                  lBu);
    async16(pU +  8 * (size_t)K, lBu +  8 * 64);
    async16(pU + 16 * (size_t)K, lBu + 16 * 64);
    async16(pU + 24 * (size_t)K, lBu + 24 * 64);
    __syncthreads();

#pragma unroll
    for (int kk = 0; kk < 2; ++kk) {
      const int pc = ((kk * 4 + q) ^ rx) * 8;
      bf16x8 af[4];
#pragma unroll
      for (int mi = 0; mi < 4; mi++)
        af[mi] = *(const bf16x8*)&sA[(wm + mi * 16 + r) * 64 + pc];
#pragma unroll
      for (int ni = 0; ni < 4; ni++) {
        bf16x8 bg = *(const bf16x8*)&sBg[(wn + ni * 16 + r) * 64 + pc];
        bf16x8 bu = *(const bf16x8*)&sBu[(wn + ni * 16 + r) * 64 + pc];
#pragma unroll
        for (int mi = 0; mi < 4; mi++) {
          accg[mi][ni] = __builtin_amdgcn_mfma_f32_16x16x32_bf16(af[mi], bg, accg[mi][ni], 0, 0, 0);
          accu[mi][ni] = __builtin_amdgcn_mfma_f32_16x16x32_bf16(af[mi], bu, accu[mi][ni], 0, 0, 0);
        }
      }
    }
    __syncthreads();
  }

#pragma unroll
  for (int ni = 0; ni < 4; ni++) {
    const int col = bN + wn + ni * 16 + r;
    const float gs = gsc[col], us = usc[col];
#pragma unroll
    for (int mi = 0; mi < 4; mi++) {
#pragma unroll
      for (int rr = 0; rr < 4; rr++) {
        const int row = bM + wm + mi * 16 + q * 4 + rr;
        float g = accg[mi][ni][rr] * gs;
        float u = accu[mi][ni][rr] * us;
        float hv = (g / (1.f + __expf(-g))) * u;   // silu(g)*u
        Hout[(size_t)row * N + col] = f2bf(hv);
      }
    }
  }
}

// ---------- schedule machinery (down GEMM) ----------
#define BAR() do { asm volatile("" ::: "memory"); __builtin_amdgcn_s_barrier(); \
                   asm volatile("" ::: "memory"); } while (0)
#define LGKM0 asm volatile("s_waitcnt lgkmcnt(0)" ::: "memory")
#define VM8   asm volatile("s_waitcnt vmcnt(8)"  ::: "memory")
#define VM10  asm volatile("s_waitcnt vmcnt(10)" ::: "memory")
#define VM0   asm volatile("s_waitcnt vmcnt(0)"  ::: "memory")

// one 128x64 bf16 half-tile = 2 global_load_lds per thread (8 waves x 16 rows)
#define STAGE2(GP, LP) do { async16((GP), (LP)); \
    async16((GP) + 8 * (size_t)K, (LP) + 8 * 64); } while (0)

#define LOAD_A(AF, CURA, HA)                                                   \
  _Pragma("unroll") for (int mi = 0; mi < 4; ++mi)                             \
  _Pragma("unroll") for (int kk = 0; kk < 2; ++kk)                             \
    AF[mi][kk] = *(const bf16x8*)&(CURA)[((HA) * 128 + wrow + mi * 16 + r) * 64 \
                                         + (((kk * 4 + q) ^ rx) * 8)];

#define LOAD_B(BF, CURB, HB)                                                   \
  _Pragma("unroll") for (int ni = 0; ni < 2; ++ni)                             \
  _Pragma("unroll") for (int kk = 0; kk < 2; ++kk)                             \
    BF[ni][kk] = *(const bf16x8*)&(CURB)[((HB) * 128 + wcol + ni * 16 + r) * 64 \
                                         + (((kk * 4 + q) ^ rx) * 8)];

#define MFMA16(ACC, AF, BF)                                                    \
  __builtin_amdgcn_s_setprio(1);                                               \
  _Pragma("unroll") for (int kk = 0; kk < 2; ++kk)                             \
  _Pragma("unroll") for (int ni = 0; ni < 2; ++ni)                             \
  _Pragma("unroll") for (int mi = 0; mi < 4; ++mi)                             \
    ACC[mi][ni] = __builtin_amdgcn_mfma_f32_16x16x32_bf16(                     \
        AF[mi][kk], BF[ni][kk], ACC[mi][ni], 0, 0, 0);                         \
  __builtin_amdgcn_s_setprio(0);

// ---------- down GEMM, 256x256, deep-pipelined ----------
// Phase order (A0,B0),(A1,B0),(A0,B1),(A1,B1): every fragment ds_read ONCE
// (24 b128/wave/K-tile). LDS regions die 1 phase after their read, so stages
// target t+2: issue->consume lag = 6-7 phases (~1500+ cy >> HBM latency).
// Stage pattern per tile t: p0->B1(t+1), p1->A0(t+2), p2->B0(t+2), p3->A1(t+2).
// One counted gate vmcnt(8) per phase (4 half-tiles in flight; guarantees
// anything issued >=4 phases ago landed; consumers need lag-6). Never vmcnt(0)
// in the main loop; explicit 2-tile drain epilogue (skipped stages would
// silently weaken counted gates).
__global__ __launch_bounds__(512, 2)
void gemm_down(const unsigned short* __restrict__ A,
               const unsigned short* __restrict__ B,
               const float* __restrict__ dsc,
               float* __restrict__ out,
               int M, int N, int K) {
  constexpr int TS = 256 * 64;          // one K-tile (A or B) in ushorts
  __shared__ unsigned short sA[2 * TS]; // 64 KiB
  __shared__ unsigned short sB[2 * TS]; // 64 KiB

  const int tid  = threadIdx.x;
  const int lane = tid & 63;
  const int wv   = tid >> 6;

  // grid = 16 x 16 = 256 blocks (one per CU); XCD-chunked bijective swizzle
  const int bid  = blockIdx.x;
  const int wgid = (bid & 7) * 32 + (bid >> 3);
  const int bM = (wgid >> 4) * 256;
  const int bN = (wgid & 15) * 256;

  const int srow = lane >> 3;
  const int gcol = ((lane & 7) ^ srow) * 8;

  const unsigned short* gA0 = A + (size_t)(bM +       wv * 16 + srow) * K + gcol;
  const unsigned short* gA1 = A + (size_t)(bM + 128 + wv * 16 + srow) * K + gcol;
  const unsigned short* gB0 = B + (size_t)(bN +       wv * 16 + srow) * K + gcol;
  const unsigned short* gB1 = B + (size_t)(bN + 128 + wv * 16 + srow) * K + gcol;

  const int r    = lane & 15;
  const int q    = lane >> 4;
  const int rx   = r & 7;
  const int wrow = (wv >> 2) * 64;
  const int wcol = (wv & 3) * 32;

  f32x4 a00[4][2], a01[4][2], a10[4][2], a11[4][2];
#pragma unroll
  for (int i = 0; i < 4; i++)
#pragma unroll
    for (int j = 0; j < 2; j++) {
      a00[i][j] = f32x4{0.f, 0.f, 0.f, 0.f};
      a01[i][j] = f32x4{0.f, 0.f, 0.f, 0.f};
      a10[i][j] = f32x4{0.f, 0.f, 0.f, 0.f};
      a11[i][j] = f32x4{0.f, 0.f, 0.f, 0.f};
    }

  const int NT = K >> 6;                // 224

  // prologue: tile0 (A0,B0,A1,B1) + tile1 (A0,B0,A1); B1(1) staged at t0.p0
  STAGE2(gA0,      &sA[       (wv * 16) * 64]);
  STAGE2(gB0,      &sB[       (wv * 16) * 64]);
  STAGE2(gA1,      &sA[(128 + wv * 16) * 64]);
  STAGE2(gB1,      &sB[(128 + wv * 16) * 64]);
  STAGE2(gA0 + 64, &sA[TS +        (wv * 16) * 64]);
  STAGE2(gB0 + 64, &sB[TS +        (wv * 16) * 64]);
  STAGE2(gA1 + 64, &sA[TS + (128 + wv * 16) * 64]);
  VM10;                                  // A0(0), B0(0) landed
  __builtin_amdgcn_s_barrier();

  // main loop: full stage pattern, counted gates only
  for (int t = 0; t < NT - 2; ++t) {
    const int cb = t & 1;
    const unsigned short* curA = sA + cb * TS;
    const unsigned short* curB = sB + cb * TS;
    unsigned short* cA = sA + cb * TS;
    unsigned short* cB = sB + cb * TS;
    unsigned short* nB = sB + (cb ^ 1) * TS;
    const size_t k1 = (size_t)(t + 1) << 6;
    const size_t k2 = (size_t)(t + 2) << 6;

    bf16x8 af0[4][2], af1[4][2], b0[2][2], b1[2][2];

    // ---- phase 0: (A0,B0) ---- stage B1(t+1) -> nxt
    LOAD_A(af0, curA, 0);
    LOAD_B(b0, curB, 0);
    STAGE2(gB1 + k1, nB + (128 + wv * 16) * 64);
    BAR(); LGKM0;
    MFMA16(a00, af0, b0);
    VM8; BAR();
    // ---- phase 1: (A1,B0) ---- stage A0(t+2) -> cur (A0(t) dead since p0)
    LOAD_A(af1, curA, 1);
    STAGE2(gA0 + k2, cA + (wv * 16) * 64);
    BAR(); LGKM0;
    MFMA16(a10, af1, b0);
    VM8; BAR();
    // ---- phase 2: (A0,B1) ---- stage B0(t+2) -> cur (B0(t) dead since p0)
    LOAD_B(b1, curB, 1);
    STAGE2(gB0 + k2, cB + (wv * 16) * 64);
    BAR(); LGKM0;
    MFMA16(a01, af0, b1);
    VM8; BAR();
    // ---- phase 3: (A1,B1) ---- stage A1(t+2) -> cur (A1(t) dead since p1)
    STAGE2(gA1 + k2, cA + (128 + wv * 16) * 64);
    BAR(); LGKM0;
    MFMA16(a11, af1, b1);
    VM8; BAR();
  }

  // drain epilogue: tiles NT-2, NT-1 (only B1(NT-1) still to stage)
  for (int t = NT - 2; t < NT; ++t) {
    const int cb = t & 1;
    const unsigned short* curA = sA + cb * TS;
    const unsigned short* curB = sB + cb * TS;
    unsigned short* nB = sB + (cb ^ 1) * TS;
    const size_t k1 = (size_t)(t + 1) << 6;

    bf16x8 af0[4][2], af1[4][2], b0[2][2], b1[2][2];

    LOAD_A(af0, curA, 0);
    LOAD_B(b0, curB, 0);
    if (t + 1 < NT) STAGE2(gB1 + k1, nB + (128 + wv * 16) * 64);
    VM0; BAR(); LGKM0;
    MFMA16(a00, af0, b0);
    BAR();
    LOAD_A(af1, curA, 1);
    BAR(); LGKM0;
    MFMA16(a10, af1, b0);
    BAR();
    LOAD_B(b1, curB, 1);
    BAR(); LGKM0;
    MFMA16(a01, af0, b1);
    BAR();
    MFMA16(a11, af1, b1);
    BAR();
  }

#pragma unroll
  for (int ni = 0; ni < 2; ++ni) {
    const int c0 = bN + wcol + ni * 16 + r;
    const int c1 = c0 + 128;
    const float s0 = dsc[c0], s1 = dsc[c1];
#pragma unroll
    for (int mi = 0; mi < 4; ++mi) {
#pragma unroll
      for (int rr = 0; rr < 4; ++rr) {
        const int row0 = bM + wrow + mi * 16 + q * 4 + rr;
        const int row1 = row0 + 128;
        out[(size_t)row0 * N + c0] = a00[mi][ni][rr] * s0;
        out[(size_t)row0 * N + c1] = a01[mi][ni][rr] * s1;
        out[(size_t)row1 * N + c0] = a10[mi][ni][rr] * s0;
        out[(size_t)row1 * N + c1] = a11[mi][ni][rr] * s1;
      }
    }
  }
}

// ---------- launch ----------
extern "C" void kernel_launch(void* const* d_in, const int* in_sizes, int n_in,
                              void* d_out, int out_size, void* d_ws, size_t ws_size,
                              hipStream_t stream) {
  constexpr int M  = 4096;   // B*S
  constexpr int Hd = 4096;   // hidden
  constexpr int Id = 14336;  // intermediate

  const float* x   = (const float*)d_in[0];
  const int*   gwq = (const int*)  d_in[1];
  const float* gsc = (const float*)d_in[2];
  const int*   uwq = (const int*)  d_in[3];
  const float* usc = (const float*)d_in[4];
  const int*   dwq = (const int*)  d_in[5];
  const float* dsc = (const float*)d_in[6];
  float* out = (float*)d_out;

  // ws layout (bf16/ushort elems): xb | w0 (gate, later down) | wu | h
  unsigned short* xb = (unsigned short*)d_ws;
  unsigned short* w0 = xb + (size_t)M * Hd;
  unsigned short* wu = w0 + (size_t)Id * Hd;
  unsigned short* hb = wu + (size_t)Id * Hd;

  cvt_f32_bf16_k<<<(M * Hd) / 1024, 256, 0, stream>>>((const float4*)x, (ushort4*)xb);
  cvt_i32_bf16_k<<<((size_t)Id * Hd) / 1024, 256, 0, stream>>>((const int4*)gwq, (ushort4*)w0);
  cvt_i32_bf16_k<<<((size_t)Id * Hd) / 1024, 256, 0, stream>>>((const int4*)uwq, (ushort4*)wu);

  // fused gate+up + SwiGLU -> h (bf16); grid = 112*32 blocks, grouped internally
  gemm_gateup<<<(Id / 128) * (M / 128), 256, 0, stream>>>(xb, w0, wu, gsc, usc, hb, M, Id, Hd);

  // reuse w0 region for down weights
  cvt_i32_bf16_k<<<((size_t)Hd * Id) / 1024, 256, 0, stream>>>((const int4*)dwq, (ushort4*)w0);

  // down GEMM -> fp32 out; 16 x 16 = 256 blocks, one per CU, XCD-swizzled
  gemm_down<<<(M / 256) * (Hd / 256), 512, 0, stream>>>(hb, w0, dsc, out, M, Hd, Id);
}